// Round 1
// baseline (39.706 us; speedup 1.0000x reference)
//
#include <hip/hip_runtime.h>

// ChannelRoll: out[row, c] = x[row, (c + m[row]) & 255], row = b*H*W + h*W + w,
// C = 256 channels, fp32. One wave (64 lanes) handles exactly one row:
// lane i produces output channels 4i..4i+3 via 4 gathered scalar loads
// (row-local, L1-resident) and one aligned float4 store (coalesced).

__global__ __launch_bounds__(256) void ChannelRoll_kernel(
    const float* __restrict__ x,
    const int*   __restrict__ shift,   // int32 per harness contract (JAX x64 off)
    float*       __restrict__ out,
    int total4)                        // total float4 elements = rows*64
{
    int gid = blockIdx.x * blockDim.x + threadIdx.x;
    if (gid >= total4) return;

    int row = gid >> 6;          // 64 float4 per 256-channel row
    int c0  = (gid & 63) << 2;   // starting output channel for this lane
    int m   = shift[row] & 255;  // wave-uniform (whole wave is one row)

    const float* xr = x + (row << 8);
    float4 v;
    v.x = xr[(c0 + 0 + m) & 255];
    v.y = xr[(c0 + 1 + m) & 255];
    v.z = xr[(c0 + 2 + m) & 255];
    v.w = xr[(c0 + 3 + m) & 255];

    reinterpret_cast<float4*>(out)[gid] = v;
}

extern "C" void kernel_launch(void* const* d_in, const int* in_sizes, int n_in,
                              void* d_out, int out_size, void* d_ws, size_t ws_size,
                              hipStream_t stream)
{
    const float* x     = (const float*)d_in[0];
    const int*   shift = (const int*)  d_in[1];
    float*       out   = (float*)d_out;

    int total4 = in_sizes[0] >> 2;            // 25,690,112 / 4 = 6,422,528
    int blocks = (total4 + 255) / 256;        // 25,088 blocks of 256 threads

    hipLaunchKernelGGL(ChannelRoll_kernel, dim3(blocks), dim3(256), 0, stream,
                       x, shift, out, total4);
}

// Round 2
// 34.907 us; speedup vs baseline: 1.1375x; 1.1375x over previous
//
#include <hip/hip_runtime.h>

// ChannelRoll: out[row, c] = x[row, (c + m[row]) & 255], C = 256 fp32, rows = B*H*W.
// One wave = one row. Fully coalesced float4 read AND write; the circular roll
// is done in-register: m = 4q + r (wave-uniform), so output slot j comes from
// source slot s=(j+r)&3 of lane (lane + q + (s<r)) & 63 -> 4 shuffles + a
// uniform slot rotation. No LDS tiles, no gather loads.

__global__ __launch_bounds__(256) void ChannelRoll_kernel(
    const float4* __restrict__ x4,
    const int*    __restrict__ shift,
    float4*       __restrict__ out4,
    int total4)
{
    int gid = blockIdx.x * blockDim.x + threadIdx.x;
    if (gid >= total4) return;

    int row  = gid >> 6;         // 64 float4 per 256-channel row
    int lane = threadIdx.x & 63; // wave-local lane == position within row

    float4 v = x4[gid];          // lane holds dwords 4*lane .. 4*lane+3 (coalesced)

    int m = shift[row] & 255;    // wave-uniform
    int q = m >> 2;
    int r = m & 3;

    // Slot s of the rotated row lives at lane (lane + q + (s < r)) & 63.
    float t0 = __shfl(v.x, (lane + q + (0 < r ? 1 : 0)) & 63, 64);
    float t1 = __shfl(v.y, (lane + q + (1 < r ? 1 : 0)) & 63, 64);
    float t2 = __shfl(v.z, (lane + q + (2 < r ? 1 : 0)) & 63, 64);
    float t3 = __shfl(v.w, (lane + q + (3 < r ? 1 : 0)) & 63, 64);

    // out slot j = t[(j + r) & 3]  (r wave-uniform -> uniform branch)
    float4 o;
    switch (r) {
        case 0:  o = make_float4(t0, t1, t2, t3); break;
        case 1:  o = make_float4(t1, t2, t3, t0); break;
        case 2:  o = make_float4(t2, t3, t0, t1); break;
        default: o = make_float4(t3, t0, t1, t2); break;
    }

    out4[gid] = o;               // coalesced
}

extern "C" void kernel_launch(void* const* d_in, const int* in_sizes, int n_in,
                              void* d_out, int out_size, void* d_ws, size_t ws_size,
                              hipStream_t stream)
{
    const float4* x4    = (const float4*)d_in[0];
    const int*    shift = (const int*)  d_in[1];
    float4*       out4  = (float4*)d_out;

    int total4 = in_sizes[0] >> 2;            // 6,422,528 (exact multiple of 256)
    int blocks = (total4 + 255) / 256;        // 25,088

    hipLaunchKernelGGL(ChannelRoll_kernel, dim3(blocks), dim3(256), 0, stream,
                       x4, shift, out4, total4);
}